// Round 1
// 194.124 us; speedup vs baseline: 1.1558x; 1.1558x over previous
//
#include <hip/hip_runtime.h>

#define DIM 128
#define NB 782            // ceil(50000/64) dst-buckets of 64 nodes
#define BCAP 1536         // fixed bucket capacity (mean ~1023, +16 sigma)
#define SC_VPT 16         // edges per thread in scatter (4096/block)

typedef __attribute__((ext_vector_type(8))) short bf16x8_t;
typedef __attribute__((ext_vector_type(4))) short bf16x4_t;
typedef __attribute__((ext_vector_type(4))) float f32x4_t;

__device__ __forceinline__ short f2bf(float f) {
    unsigned u = __float_as_uint(f);
    u += 0x7FFFu + ((u >> 16) & 1u);        // round-to-nearest-even
    return (short)(u >> 16);
}
__device__ __forceinline__ float bf2f(short s) {
    return __uint_as_float(((unsigned)(unsigned short)s) << 16);
}

// ---------------- prep: zero bucket cursors + one-time W0/W1 -> bf16 ----------
__global__ __launch_bounds__(256) void prep(const float* __restrict__ W0,
                                            const float* __restrict__ W1,
                                            short* __restrict__ W0bf,
                                            short* __restrict__ W1bf,
                                            int* __restrict__ bcursor) {
    int b = blockIdx.x, t = threadIdx.x;
    if (b == 0) {
        for (int i = t; i < NB; i += 256) bcursor[i] = 0;
    } else {
        int tid = (b - 1) * 256 + t;            // 0..2047
        for (int i = tid; i < DIM * DIM / 4; i += 2048) {
            float4 v = ((const float4*)W0)[i];
            bf16x4_t o;
            o[0] = f2bf(v.x); o[1] = f2bf(v.y); o[2] = f2bf(v.z); o[3] = f2bf(v.w);
            ((bf16x4_t*)W0bf)[i] = o;
            float4 u = ((const float4*)W1)[i];
            bf16x4_t p;
            p[0] = f2bf(u.x); p[1] = f2bf(u.y); p[2] = f2bf(u.z); p[3] = f2bf(u.w);
            ((bf16x4_t*)W1bf)[i] = p;
        }
    }
}

// ---------------- GEMM body (bf16 MFMA): Cbf[n][128] = bf16( A @ W^T ) ---------
// W pre-converted to bf16 (L2-hot, 32 KB): inner loop is 1 load + 1 MFMA per kk.
__device__ __forceinline__ void gemm_body(const float* __restrict__ A,
                                          const short* __restrict__ Wbf,
                                          short* __restrict__ Cbf, int n, int blk) {
    int wave = threadIdx.x >> 6;
    int lane = threadIdx.x & 63;
    int l16  = lane & 15;
    int quad = lane >> 4;
    int r0 = blk * 64 + wave * 16;

    int arow = r0 + l16;
    if (arow >= n) arow = n - 1;               // clamp: OOB rows never stored
    const float* Ar = A + (size_t)arow * DIM + quad * 8;

    bf16x8_t fa[4];
    #pragma unroll
    for (int kk = 0; kk < 4; kk++) {
        float4 x0 = *(const float4*)(Ar + kk * 32);
        float4 x1 = *(const float4*)(Ar + kk * 32 + 4);
        bf16x8_t f;
        f[0] = f2bf(x0.x); f[1] = f2bf(x0.y); f[2] = f2bf(x0.z); f[3] = f2bf(x0.w);
        f[4] = f2bf(x1.x); f[5] = f2bf(x1.y); f[6] = f2bf(x1.z); f[7] = f2bf(x1.w);
        fa[kk] = f;
    }

    #pragma unroll
    for (int ct = 0; ct < 8; ct++) {
        const short* Wr = Wbf + (size_t)(ct * 16 + l16) * DIM + quad * 8;
        f32x4_t acc = {0.f, 0.f, 0.f, 0.f};
        #pragma unroll
        for (int kk = 0; kk < 4; kk++) {
            bf16x8_t fb = *(const bf16x8_t*)(Wr + kk * 32);
            acc = __builtin_amdgcn_mfma_f32_16x16x32_bf16(fa[kk], fb, acc, 0, 0, 0);
        }
        #pragma unroll
        for (int j = 0; j < 4; j++) {
            int row = r0 + quad * 4 + j;
            if (row < n) Cbf[(size_t)row * DIM + ct * 16 + l16] = f2bf(acc[j]);
        }
    }
}

// ---------------- Scatter body: bin edges into fixed-cap bucket regions --------
__device__ __forceinline__ void scatter_body(const int* __restrict__ src,
                                             const int* __restrict__ dst,
                                             const float* __restrict__ norm,
                                             int* __restrict__ bcursor,
                                             int2* __restrict__ binned, int E, int blk) {
    __shared__ int hist[NB];
    __shared__ int base[NB];
    int t = threadIdx.x;
    for (int b = t; b < NB; b += 256) hist[b] = 0;
    __syncthreads();

    int e0 = blk * (256 * SC_VPT);
    int bkts[SC_VPT];
    int pack[SC_VPT];
    int nrm[SC_VPT];
    #pragma unroll
    for (int k = 0; k < SC_VPT; k++) {
        int e = e0 + k * 256 + t;               // coalesced strided reads
        if (e < E) {
            int d = dst[e];
            bkts[k] = d >> 6;
            pack[k] = ((d & 63) << 26) | src[e];
            nrm[k]  = __float_as_int(norm[e]);
            atomicAdd(&hist[bkts[k]], 1);
        } else bkts[k] = -1;
    }
    __syncthreads();
    for (int b = t; b < NB; b += 256) {
        int c = hist[b];
        base[b] = b * BCAP + (c ? atomicAdd(&bcursor[b], c) : 0);
        hist[b] = 0;
    }
    __syncthreads();
    #pragma unroll
    for (int k = 0; k < SC_VPT; k++) {
        if (bkts[k] >= 0) {
            int pos = base[bkts[k]] + atomicAdd(&hist[bkts[k]], 1);
            binned[pos] = make_int2(pack[k], nrm[k]);
        }
    }
}

// ---------------- Kernel A: gemm1 and scatter fused (independent work) ---------
__global__ __launch_bounds__(256) void fused_gemm_scatter(
        const float* __restrict__ X, const short* __restrict__ W0bf,
        short* __restrict__ Sbf, int n,
        const int* __restrict__ src, const int* __restrict__ dst,
        const float* __restrict__ norm, int* __restrict__ bcursor,
        int2* __restrict__ binned, int E, int gemmBlocks) {
    if ((int)blockIdx.x < gemmBlocks)
        gemm_body(X, W0bf, Sbf, n, blockIdx.x);
    else
        scatter_body(src, dst, norm, bcursor, binned, E, blockIdx.x - gemmBlocks);
}

// ---------------- Layer-1 propagate + fused layer-2 GEMM -----------------------
// One block (512 thr) per 64-node bucket:
//  - histogram + scan + LDS counting sort of the bucket's edges (binned read 2x,
//    coalesced, L2-hot -> no raw[] staging buffer)
//  - persist sorted edges + offsets for the layer-2 pass
//  - gather phase -> H rows (relu), NORMAL stores (stay in this XCD's L2)
//  - barrier, then the 64x128 @ 128x128 layer-2 GEMM on exactly this bucket's
//    H rows (L2-hit) -> Sbf1. 8 waves: wave w does row-tile (w&3), cts (w>>2)*4..+4.
// Writes go to Sbf1 (separate buffer) because other blocks are still gathering
// from Sbf0 -- same-buffer reuse would be a cross-block race.
__global__ __launch_bounds__(512) void prop_sort_gemm(
        const short* __restrict__ Sbf, const int2* __restrict__ binned,
        const int* __restrict__ bcnt, int2* __restrict__ edges2,
        int* __restrict__ offs_g, float* __restrict__ H,
        const short* __restrict__ W1bf, short* __restrict__ Cbf, int n) {
    __shared__ int2 eds[BCAP];          // 12 KB
    __shared__ int  hist[64];
    __shared__ int  offs_s[65];
    int b = blockIdx.x;
    int t = threadIdx.x;

    int cnt = bcnt[b];
    if (cnt > BCAP) cnt = BCAP;
    if (t < 64) hist[t] = 0;
    __syncthreads();
    const int2* eb = binned + (size_t)b * BCAP;
    for (int i = t; i < cnt; i += 512)          // pass 1: histogram only
        atomicAdd(&hist[((unsigned)eb[i].x) >> 26], 1);
    __syncthreads();
    if (t < 64) {                               // wave 0: exclusive scan
        int v = hist[t];
        int s = v;
        #pragma unroll
        for (int o = 1; o < 64; o <<= 1) {
            int x = __shfl_up(s, o, 64);
            if (t >= o) s += x;
        }
        offs_s[t] = s - v;
        if (t == 63) offs_s[64] = s;
        hist[t] = s - v;                        // becomes cursor
    }
    __syncthreads();
    for (int i = t; i < cnt; i += 512) {        // pass 2: counting sort (L2-hot re-read)
        int2 e = eb[i];
        int pos = atomicAdd(&hist[((unsigned)e.x) >> 26], 1);
        eds[pos] = e;
    }
    __syncthreads();
    int2* e2 = edges2 + (size_t)b * BCAP;       // persist for layer-2 pass
    for (int i = t; i < cnt; i += 512) e2[i] = eds[i];
    if (t < 65) offs_g[b * 65 + t] = offs_s[t];

    // ---- gather phase -> H ----
    int wv   = t >> 6;                  // 8 waves
    int lane = t & 63;
    int q    = lane >> 4;
    int l16  = lane & 15;
    int node0 = b << 6;

    for (int nd = wv; nd < 64; nd += 8) {
        int beg = offs_s[nd];
        int end = offs_s[nd + 1];
        float acc[8] = {};
        int i = beg + q;
        for (; i + 4 < end; i += 8) {
            int2 e0 = eds[i];
            int2 e1 = eds[i + 4];
            bf16x8_t v0 = *(const bf16x8_t*)(Sbf + (size_t)((unsigned)e0.x & 0x3FFFFFF) * DIM + l16 * 8);
            bf16x8_t v1 = *(const bf16x8_t*)(Sbf + (size_t)((unsigned)e1.x & 0x3FFFFFF) * DIM + l16 * 8);
            float n0 = __int_as_float(e0.y);
            float n1 = __int_as_float(e1.y);
            #pragma unroll
            for (int j = 0; j < 8; j++) acc[j] += n0 * bf2f(v0[j]);
            #pragma unroll
            for (int j = 0; j < 8; j++) acc[j] += n1 * bf2f(v1[j]);
        }
        for (; i < end; i += 4) {
            int2 e = eds[i];
            bf16x8_t v = *(const bf16x8_t*)(Sbf + (size_t)((unsigned)e.x & 0x3FFFFFF) * DIM + l16 * 8);
            float nv = __int_as_float(e.y);
            #pragma unroll
            for (int j = 0; j < 8; j++) acc[j] += nv * bf2f(v[j]);
        }
        #pragma unroll
        for (int j = 0; j < 8; j++) {
            acc[j] += __shfl_xor(acc[j], 16, 64);
            acc[j] += __shfl_xor(acc[j], 32, 64);
        }
        int node = node0 + nd;
        if (q == 0 && node < n) {
            #pragma unroll
            for (int j = 0; j < 8; j++) acc[j] = fmaxf(acc[j], 0.f);
            f32x4_t o0 = {acc[0], acc[1], acc[2], acc[3]};
            f32x4_t o1 = {acc[4], acc[5], acc[6], acc[7]};
            float* row = H + (size_t)node * DIM + l16 * 8;
            *(f32x4_t*)row = o0;                // normal store: keep in L2 for GEMM below
            *(f32x4_t*)(row + 4) = o1;
        }
    }
    __syncthreads();                            // drains vmcnt: H visible to whole block

    // ---- fused layer-2 GEMM on this bucket's rows ----
    int r0 = node0 + (wv & 3) * 16;
    int arow = r0 + l16;
    if (arow >= n) arow = n - 1;                // clamp stays inside this bucket (b=781)
    const float* Ar = H + (size_t)arow * DIM + q * 8;
    bf16x8_t fa[4];
    #pragma unroll
    for (int kk = 0; kk < 4; kk++) {
        float4 x0 = *(const float4*)(Ar + kk * 32);
        float4 x1 = *(const float4*)(Ar + kk * 32 + 4);
        bf16x8_t f;
        f[0] = f2bf(x0.x); f[1] = f2bf(x0.y); f[2] = f2bf(x0.z); f[3] = f2bf(x0.w);
        f[4] = f2bf(x1.x); f[5] = f2bf(x1.y); f[6] = f2bf(x1.z); f[7] = f2bf(x1.w);
        fa[kk] = f;
    }
    int ct0 = (wv >> 2) * 4;
    #pragma unroll
    for (int c = 0; c < 4; c++) {
        int ct = ct0 + c;
        const short* Wr = W1bf + (size_t)(ct * 16 + l16) * DIM + q * 8;
        f32x4_t acc2 = {0.f, 0.f, 0.f, 0.f};
        #pragma unroll
        for (int kk = 0; kk < 4; kk++) {
            bf16x8_t fb = *(const bf16x8_t*)(Wr + kk * 32);
            acc2 = __builtin_amdgcn_mfma_f32_16x16x32_bf16(fa[kk], fb, acc2, 0, 0, 0);
        }
        #pragma unroll
        for (int j = 0; j < 4; j++) {
            int row = r0 + q * 4 + j;
            if (row < n) Cbf[(size_t)row * DIM + ct * 16 + l16] = f2bf(acc2[j]);
        }
    }
}

// ---------------- Layer-2 propagate: pre-sorted, LDS-staged descriptors -------
__global__ __launch_bounds__(512) void prop_gather(const short* __restrict__ Sbf,
                                                   const int2* __restrict__ edges2,
                                                   const int* __restrict__ offs_g,
                                                   float* __restrict__ out, int n) {
    __shared__ int2 eds[BCAP];          // 12 KB
    __shared__ int  offs_s[65];
    int b = blockIdx.x;
    int t = threadIdx.x;

    if (t < 65) offs_s[t] = offs_g[b * 65 + t];
    __syncthreads();
    int cnt = offs_s[64];
    const int2* e2 = edges2 + (size_t)b * BCAP;
    for (int i = t; i < cnt; i += 512) eds[i] = e2[i];   // coalesced stage
    __syncthreads();

    int wv   = t >> 6;
    int lane = t & 63;
    int q    = lane >> 4;
    int l16  = lane & 15;
    int node0 = b << 6;

    for (int nd = wv; nd < 64; nd += 8) {
        int beg = offs_s[nd];
        int end = offs_s[nd + 1];
        float acc[8] = {};
        int i = beg + q;
        for (; i + 4 < end; i += 8) {
            int2 e0 = eds[i];
            int2 e1 = eds[i + 4];
            bf16x8_t v0 = *(const bf16x8_t*)(Sbf + (size_t)((unsigned)e0.x & 0x3FFFFFF) * DIM + l16 * 8);
            bf16x8_t v1 = *(const bf16x8_t*)(Sbf + (size_t)((unsigned)e1.x & 0x3FFFFFF) * DIM + l16 * 8);
            float n0 = __int_as_float(e0.y);
            float n1 = __int_as_float(e1.y);
            #pragma unroll
            for (int j = 0; j < 8; j++) acc[j] += n0 * bf2f(v0[j]);
            #pragma unroll
            for (int j = 0; j < 8; j++) acc[j] += n1 * bf2f(v1[j]);
        }
        for (; i < end; i += 4) {
            int2 e = eds[i];
            bf16x8_t v = *(const bf16x8_t*)(Sbf + (size_t)((unsigned)e.x & 0x3FFFFFF) * DIM + l16 * 8);
            float nv = __int_as_float(e.y);
            #pragma unroll
            for (int j = 0; j < 8; j++) acc[j] += nv * bf2f(v[j]);
        }
        #pragma unroll
        for (int j = 0; j < 8; j++) {
            acc[j] += __shfl_xor(acc[j], 16, 64);
            acc[j] += __shfl_xor(acc[j], 32, 64);
        }
        int node = node0 + nd;
        if (q == 0 && node < n) {
            f32x4_t o0 = {acc[0], acc[1], acc[2], acc[3]};
            f32x4_t o1 = {acc[4], acc[5], acc[6], acc[7]};
            float* row = out + (size_t)node * DIM + l16 * 8;
            __builtin_nontemporal_store(o0, (f32x4_t*)row);
            __builtin_nontemporal_store(o1, (f32x4_t*)(row + 4));
        }
    }
}

// ---------------- launch ----------------

extern "C" void kernel_launch(void* const* d_in, const int* in_sizes, int n_in,
                              void* d_out, int out_size, void* d_ws, size_t ws_size,
                              hipStream_t stream) {
    const float* X    = (const float*)d_in[0];
    const float* W0   = (const float*)d_in[1];
    const float* W1   = (const float*)d_in[2];
    const float* norm = (const float*)d_in[3];
    const int*   src  = (const int*)d_in[4];
    const int*   dst  = (const int*)d_in[5];

    const int N = in_sizes[0] / DIM;   // 50000
    const int E = in_sizes[3];         // 800000

    float* Z = (float*)d_out;
    float* H = (float*)d_out + (size_t)N * DIM;

    // workspace layout (~45.3 MB)
    char* ws = (char*)d_ws;
    short* Sbf0   = (short*)ws;                      // 12.8 MB  layer-1 scores
    size_t off    = (size_t)N * DIM * sizeof(short);
    short* Sbf1   = (short*)(ws + off); off += (size_t)N * DIM * sizeof(short);  // 12.8 MB layer-2 scores
    short* W0bf   = (short*)(ws + off); off += (size_t)DIM * DIM * sizeof(short);
    short* W1bf   = (short*)(ws + off); off += (size_t)DIM * DIM * sizeof(short);
    int*   bcursor= (int*)(ws + off); off += (NB * 4 + 255) / 256 * 256;
    int*   offs_g = (int*)(ws + off); off += ((size_t)NB * 65 * 4 + 255) / 256 * 256;
    int2*  binned = (int2*)(ws + off); off += (size_t)NB * BCAP * 8;
    int2*  edges2 = (int2*)(ws + off); off += (size_t)NB * BCAP * 8;

    const int gemmBlocks = (N + 63) / 64;            // 782
    const int scBlocks   = (E + 256 * SC_VPT - 1) / (256 * SC_VPT);  // 196

    // 0. zero bucket cursors + one-time bf16 conversion of W0/W1
    prep<<<9, 256, 0, stream>>>(W0, W1, W0bf, W1bf, bcursor);
    // 1. layer-1 GEMM fused with edge bucket-sort (independent work, one dispatch)
    fused_gemm_scatter<<<gemmBlocks + scBlocks, 256, 0, stream>>>(
        X, W0bf, Sbf0, N, src, dst, norm, bcursor, binned, E, gemmBlocks);
    // 2. layer-1 propagate (sort + gather -> H) fused with layer-2 GEMM -> Sbf1
    prop_sort_gemm<<<NB, 512, 0, stream>>>(Sbf0, binned, bcursor, edges2, offs_g,
                                           H, W1bf, Sbf1, N);
    // 3. layer-2 propagate (pre-sorted, LDS-staged) -> Z
    prop_gather<<<NB, 512, 0, stream>>>(Sbf1, edges2, offs_g, Z, N);
}